// Round 3
// baseline (129.681 us; speedup 1.0000x reference)
//
#include <hip/hip_runtime.h>

#define NLOG2E -1.44269504088896340736f

typedef float f32x2 __attribute__((ext_vector_type(2)));

// Round 3 structure:
//  - prefold kernel -> d_ws (69 folded floats, s_load'ed to SGPRs in main).
//  - main kernel: PERSISTENT grid-stride with depth-1 prefetch.
//    Round 0/1/2 post-mortem: all one-shot variants land at ~35-44 us vs a
//    ~16 us HBM floor, latency-bound (VALUBusy 43%, HBM 19%) -- each wave
//    issues its loads once, stalls, then computes with nothing in flight
//    (loads-in-flight duty cycle ~30% < BW*latency requirement).
//    Grid-stride + prefetch keeps ~1 KB/wave outstanding continuously:
//    24-32 KB/CU in flight >> 9.2 KB (6.3 TB/s x 375 ns), so HBM saturates
//    while the packed-f32x2 body executes under the latency.
//
// ws layout (floats): [0:8)=uw0 [8:16)=uw1 [16:24)=ub [24:56)=w2f
//                     [56:60)=b2 [60:64)=ncl2 [64:68)=aw2 [68]=bb3

__global__ void prefold_kernel(
    const float* __restrict__ W1, const float* __restrict__ b1,
    const float* __restrict__ a1, const float* __restrict__ c1,
    const float* __restrict__ W2, const float* __restrict__ b2,
    const float* __restrict__ a2, const float* __restrict__ c2,
    const float* __restrict__ W3, const float* __restrict__ b3,
    float* __restrict__ C)
{
    if (threadIdx.x == 0 && blockIdx.x == 0) {
        for (int j = 0; j < 8; ++j) {
            float ncl = c1[j] * NLOG2E;
            C[j]      = W1[j]     * ncl;
            C[8 + j]  = W1[8 + j] * ncl;
            C[16 + j] = b1[j]     * ncl;
            float k1 = a1[j] / ncl;
            for (int k = 0; k < 4; ++k)
                C[24 + j * 4 + k] = W2[j * 4 + k] * k1;
        }
        for (int k = 0; k < 4; ++k) {
            C[56 + k] = b2[k];
            C[60 + k] = c2[k] * NLOG2E;
            C[64 + k] = a2[k] * W3[k];
        }
        C[68] = b3[0];
    }
}

// One 2-row slot: rows (p.x,p.y) and (p.z,p.w) -> f32x2 of outputs.
// Proven packed body (pk_fma/pk_add/pk_mul + scalar exp2/rcp), unchanged.
__device__ __forceinline__ f32x2 moth2(float4 p, const f32x2* __restrict__ Cp,
                                       float bb3)
{
    // stage 1: u-values, 2 rows x 4 j-pairs of pk_fma
    f32x2 u[2][4];
#pragma unroll
    for (int r = 0; r < 2; ++r) {
        float X0 = r ? p.z : p.x;
        float X1 = r ? p.w : p.y;
        f32x2 x0b = {X0, X0};
        f32x2 x1b = {X1, X1};
#pragma unroll
        for (int pj = 0; pj < 4; ++pj)
            u[r][pj] = __builtin_elementwise_fma(
                           x0b, Cp[pj],
                           __builtin_elementwise_fma(x1b, Cp[4 + pj],
                                                     Cp[8 + pj]));
    }

    // stage 2: h_eff = u * rcp(1 + exp2(u)); trans scalar, rest packed
#pragma unroll
    for (int r = 0; r < 2; ++r)
#pragma unroll
        for (int pj = 0; pj < 4; ++pj) {
            f32x2 e;
            e[0] = __builtin_amdgcn_exp2f(u[r][pj][0]);
            e[1] = __builtin_amdgcn_exp2f(u[r][pj][1]);
            f32x2 d = e + 1.0f;                    // pk_add
            f32x2 s;
            s[0] = __builtin_amdgcn_rcpf(d[0]);
            s[1] = __builtin_amdgcn_rcpf(d[1]);
            u[r][pj] *= s;                         // pk_mul, h_eff
        }

    // stages 3+4: layer-2 dot-8, second activation, final reduce
    f32x2 res;
#pragma unroll
    for (int r = 0; r < 2; ++r) {
        f32x2 ta = Cp[28], tb = Cp[29];            // b2 pairs
#pragma unroll
        for (int j = 0; j < 8; ++j) {
            float hj = u[r][j >> 1][j & 1];
            f32x2 hb = {hj, hj};
            ta = __builtin_elementwise_fma(hb, Cp[12 + j * 2 + 0], ta);
            tb = __builtin_elementwise_fma(hb, Cp[12 + j * 2 + 1], tb);
        }
        f32x2 u2a = Cp[30] * ta;                   // ncl2 pairs
        f32x2 u2b = Cp[31] * tb;
        f32x2 ea, eb;
        ea[0] = __builtin_amdgcn_exp2f(u2a[0]);
        ea[1] = __builtin_amdgcn_exp2f(u2a[1]);
        eb[0] = __builtin_amdgcn_exp2f(u2b[0]);
        eb[1] = __builtin_amdgcn_exp2f(u2b[1]);
        f32x2 da = ea + 1.0f, db = eb + 1.0f;
        f32x2 sa, sb;
        sa[0] = __builtin_amdgcn_rcpf(da[0]);
        sa[1] = __builtin_amdgcn_rcpf(da[1]);
        sb[0] = __builtin_amdgcn_rcpf(db[0]);
        sb[1] = __builtin_amdgcn_rcpf(db[1]);
        f32x2 pa = ta * sa;                        // pk_mul
        f32x2 pb = tb * sb;
        f32x2 acc = {bb3, 0.0f};
        acc = __builtin_elementwise_fma(pa, Cp[32], acc);
        acc = __builtin_elementwise_fma(pb, Cp[33], acc);
        res[r] = acc[0] + acc[1];
    }
    return res;
}

__global__ __launch_bounds__(256, 6) void PlaygroundModel_66365834658304_kernel(
    const float* __restrict__ x, const float* __restrict__ C,
    float* __restrict__ out, int rows)
{
    const f32x2* Cp = (const f32x2*)C;
    float bb3 = C[68];

    long long n4f    = (long long)rows >> 1;              // full 2-row groups
    long long g      = (long long)blockIdx.x * blockDim.x + threadIdx.x;
    long long stride = (long long)gridDim.x * blockDim.x;

    const float4* x4 = (const float4*)x;
    f32x2* o2 = (f32x2*)out;

    long long idx = g;
    if (idx < n4f) {
        float4 p = x4[idx];                // first load
        for (;;) {
            long long nidx = idx + stride;
            bool has = (nidx < n4f);
            float4 np;
            if (has) np = x4[nidx];        // prefetch next tile: issued
                                           // BEFORE the ~400-cyc compute body,
                                           // consumed AFTER it -> latency hidden
            o2[idx] = moth2(p, Cp, bb3);   // compute + coalesced 8B store
            if (!has) break;
            p = np;
            idx = nidx;
        }
    }

    // odd trailing row (not hit for B = 8388608)
    if (g == 0 && (rows & 1)) {
        const float* uw0  = C;
        const float* uw1  = C + 8;
        const float* ub   = C + 16;
        const float* w2f  = C + 24;
        const float* bb2  = C + 56;
        const float* ncl2 = C + 60;
        const float* aw2  = C + 64;
        long long rr = (long long)rows - 1;
        float x0 = x[rr * 2 + 0], x1 = x[rr * 2 + 1];
        float h[8];
#pragma unroll
        for (int j = 0; j < 8; ++j) {
            float uu = fmaf(x0, uw0[j], fmaf(x1, uw1[j], ub[j]));
            float s  = __builtin_amdgcn_rcpf(
                           1.0f + __builtin_amdgcn_exp2f(uu));
            h[j] = uu * s;
        }
        float o = bb3;
#pragma unroll
        for (int kk = 0; kk < 4; ++kk) {
            float t = bb2[kk];
#pragma unroll
            for (int j = 0; j < 8; ++j) t = fmaf(h[j], w2f[j * 4 + kk], t);
            float u2 = ncl2[kk] * t;
            float sg = __builtin_amdgcn_rcpf(
                           1.0f + __builtin_amdgcn_exp2f(u2));
            o = fmaf(t * sg, aw2[kk], o);
        }
        out[rr] = o;
    }
}

extern "C" void kernel_launch(void* const* d_in, const int* in_sizes, int n_in,
                              void* d_out, int out_size, void* d_ws, size_t ws_size,
                              hipStream_t stream) {
    const float* x  = (const float*)d_in[0];
    const float* W1 = (const float*)d_in[1];
    const float* b1 = (const float*)d_in[2];
    const float* a1 = (const float*)d_in[3];
    const float* c1 = (const float*)d_in[4];
    const float* W2 = (const float*)d_in[5];
    const float* b2 = (const float*)d_in[6];
    const float* a2 = (const float*)d_in[7];
    const float* c2 = (const float*)d_in[8];
    const float* W3 = (const float*)d_in[9];
    const float* b3 = (const float*)d_in[10];
    float* out = (float*)d_out;
    float* C   = (float*)d_ws;

    prefold_kernel<<<1, 64, 0, stream>>>(W1, b1, a1, c1, W2, b2, a2, c2,
                                         W3, b3, C);

    int rows = in_sizes[0] / 2;
    long long n4 = (long long)rows >> 1;           // 2-row groups

    // persistent-ish grid: ~4 groups per thread, capped at 4096 blocks
    // (16 blocks/CU -> small tail quantum), min 1.
    int block = 256;
    long long want = (n4 + (long long)block * 4 - 1) / ((long long)block * 4);
    int grid = (int)(want < 1 ? 1 : (want > 4096 ? 4096 : want));

    PlaygroundModel_66365834658304_kernel<<<grid, block, 0, stream>>>(
        x, C, out, rows);
}

// Round 4
// 129.249 us; speedup vs baseline: 1.0033x; 1.0033x over previous
//
#include <hip/hip_runtime.h>

#define NLOG2E -1.44269504088896340736f

typedef float f32x2 __attribute__((ext_vector_type(2)));

// Round 4 structure:
//  - prefold kernel -> d_ws (69 folded floats; main kernel s_loads them into
//    SGPRs -- proven fastest constant path, R0 vs R1).
//  - main kernel: EXACTLY-RESIDENT persistent grid (1536 blocks = 6/CU at
//    launch_bounds(256,6), 24 waves/CU, single generation) with DEPTH-2
//    register prefetch (load for iter i+2 issued before computing iter i:
//    ~1100 cyc cover vs ~900 cyc HBM latency; 24 KB/CU continuously in
//    flight > 9.2 KB BW*latency product) and pure 32-bit index arithmetic
//    (one v_add per pointer per iteration; R3's long-long math was multi-
//    instruction 64-bit chains in the hot loop).
//
// ws layout (floats): [0:8)=uw0 [8:16)=uw1 [16:24)=ub [24:56)=w2f
//                     [56:60)=b2 [60:64)=ncl2 [64:68)=aw2 [68]=bb3

__global__ void prefold_kernel(
    const float* __restrict__ W1, const float* __restrict__ b1,
    const float* __restrict__ a1, const float* __restrict__ c1,
    const float* __restrict__ W2, const float* __restrict__ b2,
    const float* __restrict__ a2, const float* __restrict__ c2,
    const float* __restrict__ W3, const float* __restrict__ b3,
    float* __restrict__ C)
{
    if (threadIdx.x == 0 && blockIdx.x == 0) {
        for (int j = 0; j < 8; ++j) {
            float ncl = c1[j] * NLOG2E;
            C[j]      = W1[j]     * ncl;
            C[8 + j]  = W1[8 + j] * ncl;
            C[16 + j] = b1[j]     * ncl;
            float k1 = a1[j] / ncl;
            for (int k = 0; k < 4; ++k)
                C[24 + j * 4 + k] = W2[j * 4 + k] * k1;
        }
        for (int k = 0; k < 4; ++k) {
            C[56 + k] = b2[k];
            C[60 + k] = c2[k] * NLOG2E;
            C[64 + k] = a2[k] * W3[k];
        }
        C[68] = b3[0];
    }
}

// One 2-row slot: rows (p.x,p.y) and (p.z,p.w) -> f32x2 of outputs.
// Proven packed body (pk_fma/pk_add/pk_mul + scalar exp2/rcp), unchanged.
__device__ __forceinline__ f32x2 moth2(float4 p, const f32x2* __restrict__ Cp,
                                       float bb3)
{
    // stage 1: u-values, 2 rows x 4 j-pairs of pk_fma
    f32x2 u[2][4];
#pragma unroll
    for (int r = 0; r < 2; ++r) {
        float X0 = r ? p.z : p.x;
        float X1 = r ? p.w : p.y;
        f32x2 x0b = {X0, X0};
        f32x2 x1b = {X1, X1};
#pragma unroll
        for (int pj = 0; pj < 4; ++pj)
            u[r][pj] = __builtin_elementwise_fma(
                           x0b, Cp[pj],
                           __builtin_elementwise_fma(x1b, Cp[4 + pj],
                                                     Cp[8 + pj]));
    }

    // stage 2: h_eff = u * rcp(1 + exp2(u)); trans scalar, rest packed
#pragma unroll
    for (int r = 0; r < 2; ++r)
#pragma unroll
        for (int pj = 0; pj < 4; ++pj) {
            f32x2 e;
            e[0] = __builtin_amdgcn_exp2f(u[r][pj][0]);
            e[1] = __builtin_amdgcn_exp2f(u[r][pj][1]);
            f32x2 d = e + 1.0f;                    // pk_add
            f32x2 s;
            s[0] = __builtin_amdgcn_rcpf(d[0]);
            s[1] = __builtin_amdgcn_rcpf(d[1]);
            u[r][pj] *= s;                         // pk_mul, h_eff
        }

    // stages 3+4: layer-2 dot-8, second activation, final reduce
    f32x2 res;
#pragma unroll
    for (int r = 0; r < 2; ++r) {
        f32x2 ta = Cp[28], tb = Cp[29];            // b2 pairs
#pragma unroll
        for (int j = 0; j < 8; ++j) {
            float hj = u[r][j >> 1][j & 1];
            f32x2 hb = {hj, hj};
            ta = __builtin_elementwise_fma(hb, Cp[12 + j * 2 + 0], ta);
            tb = __builtin_elementwise_fma(hb, Cp[12 + j * 2 + 1], tb);
        }
        f32x2 u2a = Cp[30] * ta;                   // ncl2 pairs
        f32x2 u2b = Cp[31] * tb;
        f32x2 ea, eb;
        ea[0] = __builtin_amdgcn_exp2f(u2a[0]);
        ea[1] = __builtin_amdgcn_exp2f(u2a[1]);
        eb[0] = __builtin_amdgcn_exp2f(u2b[0]);
        eb[1] = __builtin_amdgcn_exp2f(u2b[1]);
        f32x2 da = ea + 1.0f, db = eb + 1.0f;
        f32x2 sa, sb;
        sa[0] = __builtin_amdgcn_rcpf(da[0]);
        sa[1] = __builtin_amdgcn_rcpf(da[1]);
        sb[0] = __builtin_amdgcn_rcpf(db[0]);
        sb[1] = __builtin_amdgcn_rcpf(db[1]);
        f32x2 pa = ta * sa;                        // pk_mul
        f32x2 pb = tb * sb;
        f32x2 acc = {bb3, 0.0f};
        acc = __builtin_elementwise_fma(pa, Cp[32], acc);
        acc = __builtin_elementwise_fma(pb, Cp[33], acc);
        res[r] = acc[0] + acc[1];
    }
    return res;
}

__global__ __launch_bounds__(256, 6) void PlaygroundModel_66365834658304_kernel(
    const float* __restrict__ x, const float* __restrict__ C,
    float* __restrict__ out, int rows)
{
    const f32x2* Cp = (const f32x2*)C;
    float bb3 = C[68];

    int n4   = rows >> 1;                      // float4 slots (2 rows each)
    int n4m1 = n4 - 1;
    int T    = (int)(gridDim.x * blockDim.x);  // total threads (stride)
    int g    = (int)(blockIdx.x * blockDim.x + threadIdx.x);

    const float4* x4 = (const float4*)x;
    f32x2* o2 = (f32x2*)out;

    if (g < n4) {
        // depth-2 register prefetch pipeline, branch-free clamped loads
        int i0 = g;
        int i1 = (i0 + T <= n4m1) ? i0 + T : n4m1;
        float4 A = x4[i0];
        float4 B = x4[i1];
        int idx = i0, nxt = i0 + T;
        while (true) {
            int nn = nxt + T;
            int ld = (nn <= n4m1) ? nn : n4m1;  // clamp: harmless dup load
            float4 Cq = x4[ld];
            o2[idx] = moth2(A, Cp, bb3);        // compute + coalesced store
            if (nxt > n4m1) break;
            A = B; B = Cq;
            idx = nxt; nxt = nn;
        }
    }

    // odd trailing row (not hit for B = 8388608)
    if (g == 0 && (rows & 1)) {
        const float* uw0  = C;
        const float* uw1  = C + 8;
        const float* ub   = C + 16;
        const float* w2f  = C + 24;
        const float* bb2  = C + 56;
        const float* ncl2 = C + 60;
        const float* aw2  = C + 64;
        int rr = rows - 1;
        float x0 = x[(size_t)rr * 2 + 0], x1 = x[(size_t)rr * 2 + 1];
        float h[8];
#pragma unroll
        for (int j = 0; j < 8; ++j) {
            float uu = fmaf(x0, uw0[j], fmaf(x1, uw1[j], ub[j]));
            float s  = __builtin_amdgcn_rcpf(
                           1.0f + __builtin_amdgcn_exp2f(uu));
            h[j] = uu * s;
        }
        float o = bb3;
#pragma unroll
        for (int kk = 0; kk < 4; ++kk) {
            float t = bb2[kk];
#pragma unroll
            for (int j = 0; j < 8; ++j) t = fmaf(h[j], w2f[j * 4 + kk], t);
            float u2 = ncl2[kk] * t;
            float sg = __builtin_amdgcn_rcpf(
                           1.0f + __builtin_amdgcn_exp2f(u2));
            o = fmaf(t * sg, aw2[kk], o);
        }
        out[rr] = o;
    }
}

extern "C" void kernel_launch(void* const* d_in, const int* in_sizes, int n_in,
                              void* d_out, int out_size, void* d_ws, size_t ws_size,
                              hipStream_t stream) {
    const float* x  = (const float*)d_in[0];
    const float* W1 = (const float*)d_in[1];
    const float* b1 = (const float*)d_in[2];
    const float* a1 = (const float*)d_in[3];
    const float* c1 = (const float*)d_in[4];
    const float* W2 = (const float*)d_in[5];
    const float* b2 = (const float*)d_in[6];
    const float* a2 = (const float*)d_in[7];
    const float* c2 = (const float*)d_in[8];
    const float* W3 = (const float*)d_in[9];
    const float* b3 = (const float*)d_in[10];
    float* out = (float*)d_out;
    float* C   = (float*)d_ws;

    prefold_kernel<<<1, 64, 0, stream>>>(W1, b1, a1, c1, W2, b2, a2, c2,
                                         W3, b3, C);

    int rows = in_sizes[0] / 2;
    int n4   = rows >> 1;                      // float4 slots

    // exactly-resident persistent grid: 6 blocks/CU x 256 CU = 1536 blocks
    // (launch_bounds(256,6) -> 24 waves/CU), single generation, ~11 iters/thread
    int block = 256;
    int grid  = 1536;
    int need  = (n4 + block - 1) / block;
    if (need < grid) grid = need;
    if (grid < 1) grid = 1;

    PlaygroundModel_66365834658304_kernel<<<grid, block, 0, stream>>>(
        x, C, out, rows);
}

// Round 5
// 128.797 us; speedup vs baseline: 1.0069x; 1.0035x over previous
//
#include <hip/hip_runtime.h>

#define NLOG2E -1.44269504088896340736f

typedef float f32x2 __attribute__((ext_vector_type(2)));

// Round 5:
//  - Memory structure proven irrelevant (R1-R4: one-shot, wave-strided,
//    grid-stride d1, persistent d2 all ~39-44 us). Kernel is issue-bound
//    (likely at throttled shader clock; VALUBusy 43% == full issue if SQ
//    counts at shader clock vs GRBM reference). Lever: issued cycles.
//  - Trans ops = 70% of issue. exp2 count irreducible; rcp count cut 4x via
//    quad-rcp: one v_rcp_f32 of the product d1*d2*d3*d4 + 6 pk/scalar muls
//    reconstructs all four reciprocals (element swizzles of f32x2 are free:
//    elements live in separate VGPRs). 548 -> 464 cyc per 2-row slot (-15%).
//    Overflow-safe: d in [1, 2^26] -> product <= 2^104; d >= 1 so P >= 1.
//  - Structure: R2's proven one-shot, 8 rows/thread, 4 wave-strided float4
//    slots (loads/stores fold into immediate offsets).
//
// ws layout (floats): [0:8)=uw0 [8:16)=uw1 [16:24)=ub [24:56)=w2f
//                     [56:60)=b2 [60:64)=ncl2 [64:68)=aw2 [68]=bb3

__global__ void prefold_kernel(
    const float* __restrict__ W1, const float* __restrict__ b1,
    const float* __restrict__ a1, const float* __restrict__ c1,
    const float* __restrict__ W2, const float* __restrict__ b2,
    const float* __restrict__ a2, const float* __restrict__ c2,
    const float* __restrict__ W3, const float* __restrict__ b3,
    float* __restrict__ C)
{
    if (threadIdx.x == 0 && blockIdx.x == 0) {
        for (int j = 0; j < 8; ++j) {
            float ncl = c1[j] * NLOG2E;
            C[j]      = W1[j]     * ncl;
            C[8 + j]  = W1[8 + j] * ncl;
            C[16 + j] = b1[j]     * ncl;
            float k1 = a1[j] / ncl;
            for (int k = 0; k < 4; ++k)
                C[24 + j * 4 + k] = W2[j * 4 + k] * k1;
        }
        for (int k = 0; k < 4; ++k) {
            C[56 + k] = b2[k];
            C[60 + k] = c2[k] * NLOG2E;
            C[64 + k] = a2[k] * W3[k];
        }
        C[68] = b3[0];
    }
}

// Four reciprocals from ONE v_rcp_f32.
// da={d1,d2}, db={d3,d4} (all >= 1). Returns sa={1/d1,1/d2}, sb={1/d3,1/d4}.
// P = d1d2d3d4; 1/d1 = d2d3d4*r = (d2d4)*d3*r, etc. Element swizzles free.
__device__ __forceinline__ void quad_rcp(f32x2 da, f32x2 db,
                                         f32x2& sa, f32x2& sb)
{
    f32x2 Pp = da * db;                  // {d1*d3, d2*d4}     pk_mul
    float P  = Pp[0] * Pp[1];            // d1*d2*d3*d4        mul
    float r  = __builtin_amdgcn_rcpf(P); //                    1 trans (was 4)
    f32x2 m1 = {Pp[1], Pp[0]};           // free swizzle
    f32x2 rv = {r, r};                   // free splat
    sa = (m1 * db) * rv;                 // {d2d3d4, d1d3d4}*r = {1/d1, 1/d2}
    sb = (m1 * da) * rv;                 // {d1d2d4, d1d2d3}*r = {1/d3, 1/d4}
}

// One 2-row slot: rows (p.x,p.y) and (p.z,p.w) -> f32x2 of outputs.
__device__ __forceinline__ f32x2 moth2(float4 p, const f32x2* __restrict__ Cp,
                                       float bb3)
{
    // stage 1: u-values, 2 rows x 4 j-pairs of pk_fma
    f32x2 u[2][4];
#pragma unroll
    for (int r = 0; r < 2; ++r) {
        float X0 = r ? p.z : p.x;
        float X1 = r ? p.w : p.y;
        f32x2 x0b = {X0, X0};
        f32x2 x1b = {X1, X1};
#pragma unroll
        for (int pj = 0; pj < 4; ++pj)
            u[r][pj] = __builtin_elementwise_fma(
                           x0b, Cp[pj],
                           __builtin_elementwise_fma(x1b, Cp[4 + pj],
                                                     Cp[8 + pj]));
    }

    // stage 2: h = u * sigma(u'), sigma = rcp(1+exp2(u')).
    // 8 exp2/row (irreducible) + 2 quad_rcp/row (was 8 rcp/row).
#pragma unroll
    for (int r = 0; r < 2; ++r) {
        f32x2 d[4];
#pragma unroll
        for (int pj = 0; pj < 4; ++pj) {
            f32x2 e;
            e[0] = __builtin_amdgcn_exp2f(u[r][pj][0]);
            e[1] = __builtin_amdgcn_exp2f(u[r][pj][1]);
            d[pj] = e + 1.0f;                      // pk_add
        }
        f32x2 s0, s1, s2, s3;
        quad_rcp(d[0], d[1], s0, s1);
        quad_rcp(d[2], d[3], s2, s3);
        u[r][0] *= s0;                             // pk_mul, h_eff
        u[r][1] *= s1;
        u[r][2] *= s2;
        u[r][3] *= s3;
    }

    // stages 3+4: layer-2 dot-8, second activation (quad_rcp), final reduce
    f32x2 res;
#pragma unroll
    for (int r = 0; r < 2; ++r) {
        f32x2 ta = Cp[28], tb = Cp[29];            // b2 pairs
#pragma unroll
        for (int j = 0; j < 8; ++j) {
            float hj = u[r][j >> 1][j & 1];
            f32x2 hb = {hj, hj};
            ta = __builtin_elementwise_fma(hb, Cp[12 + j * 2 + 0], ta);
            tb = __builtin_elementwise_fma(hb, Cp[12 + j * 2 + 1], tb);
        }
        f32x2 u2a = Cp[30] * ta;                   // ncl2 pairs
        f32x2 u2b = Cp[31] * tb;
        f32x2 ea, eb;
        ea[0] = __builtin_amdgcn_exp2f(u2a[0]);
        ea[1] = __builtin_amdgcn_exp2f(u2a[1]);
        eb[0] = __builtin_amdgcn_exp2f(u2b[0]);
        eb[1] = __builtin_amdgcn_exp2f(u2b[1]);
        f32x2 da = ea + 1.0f, db = eb + 1.0f;
        f32x2 sa, sb;
        quad_rcp(da, db, sa, sb);                  // 1 rcp (was 4)
        f32x2 pa = ta * sa;                        // pk_mul
        f32x2 pb = tb * sb;
        f32x2 acc = {bb3, 0.0f};
        acc = __builtin_elementwise_fma(pa, Cp[32], acc);
        acc = __builtin_elementwise_fma(pb, Cp[33], acc);
        res[r] = acc[0] + acc[1];
    }
    return res;
}

__global__ __launch_bounds__(256, 4) void PlaygroundModel_66365834658304_kernel(
    const float* __restrict__ x, const float* __restrict__ C,
    float* __restrict__ out, int rows)
{
    const f32x2* Cp = (const f32x2*)C;
    float bb3 = C[68];

    int g = blockIdx.x * blockDim.x + threadIdx.x;
    int lane = g & 63;
    long long idx0 = (long long)(g >> 6) * 256 + lane;  // wave-strided slot 0
    long long n4f  = (long long)rows >> 1;              // full 2-row groups

    const float4* x4 = (const float4*)x;
    f32x2* o2 = (f32x2*)out;

    if (idx0 + 192 < n4f) {
        // 4 upfront loads, each perfectly coalesced (16 B/lane); +64/+128/+192
        // fold into 13-bit immediate offsets off one base address.
        float4 P0 = x4[idx0];
        float4 P1 = x4[idx0 + 64];
        float4 P2 = x4[idx0 + 128];
        float4 P3 = x4[idx0 + 192];
        o2[idx0]       = moth2(P0, Cp, bb3);
        o2[idx0 + 64]  = moth2(P1, Cp, bb3);
        o2[idx0 + 128] = moth2(P2, Cp, bb3);
        o2[idx0 + 192] = moth2(P3, Cp, bb3);
    } else {
        // boundary wave: scalar per-row fallback (only the final partial wave)
        const float* uw0  = C;
        const float* uw1  = C + 8;
        const float* ub   = C + 16;
        const float* w2f  = C + 24;
        const float* bb2  = C + 56;
        const float* ncl2 = C + 60;
        const float* aw2  = C + 64;
#pragma unroll
        for (int k = 0; k < 4; ++k) {
            long long idx = idx0 + 64 * k;
            long long r0 = idx * 2;
            for (long long rr = r0; rr < r0 + 2 && rr < rows; ++rr) {
                float x0 = x[rr * 2 + 0], x1 = x[rr * 2 + 1];
                float h[8];
#pragma unroll
                for (int j = 0; j < 8; ++j) {
                    float uu = fmaf(x0, uw0[j], fmaf(x1, uw1[j], ub[j]));
                    float s  = __builtin_amdgcn_rcpf(
                                   1.0f + __builtin_amdgcn_exp2f(uu));
                    h[j] = uu * s;
                }
                float o = bb3;
#pragma unroll
                for (int kk = 0; kk < 4; ++kk) {
                    float t = bb2[kk];
#pragma unroll
                    for (int j = 0; j < 8; ++j)
                        t = fmaf(h[j], w2f[j * 4 + kk], t);
                    float u2 = ncl2[kk] * t;
                    float sg = __builtin_amdgcn_rcpf(
                                   1.0f + __builtin_amdgcn_exp2f(u2));
                    o = fmaf(t * sg, aw2[kk], o);
                }
                out[rr] = o;
            }
        }
    }
}

extern "C" void kernel_launch(void* const* d_in, const int* in_sizes, int n_in,
                              void* d_out, int out_size, void* d_ws, size_t ws_size,
                              hipStream_t stream) {
    const float* x  = (const float*)d_in[0];
    const float* W1 = (const float*)d_in[1];
    const float* b1 = (const float*)d_in[2];
    const float* a1 = (const float*)d_in[3];
    const float* c1 = (const float*)d_in[4];
    const float* W2 = (const float*)d_in[5];
    const float* b2 = (const float*)d_in[6];
    const float* a2 = (const float*)d_in[7];
    const float* c2 = (const float*)d_in[8];
    const float* W3 = (const float*)d_in[9];
    const float* b3 = (const float*)d_in[10];
    float* out = (float*)d_out;
    float* C   = (float*)d_ws;

    prefold_kernel<<<1, 64, 0, stream>>>(W1, b1, a1, c1, W2, b2, a2, c2,
                                         W3, b3, C);

    int rows = in_sizes[0] / 2;
    long long n4    = ((long long)rows + 1) / 2;   // 2-row groups (incl. partial)
    long long waves = (n4 + 255) / 256;            // 256 groups per wave
    long long thr   = waves * 64;
    int block = 256;
    long long grid = (thr + block - 1) / block;
    if (grid < 1) grid = 1;

    PlaygroundModel_66365834658304_kernel<<<(int)grid, block, 0, stream>>>(
        x, C, out, rows);
}